// Round 16
// baseline (392.019 us; speedup 1.0000x reference)
//
#include <hip/hip_runtime.h>
#include <hip/hip_bf16.h>

#define B_  2048
#define T_  200
#define D_  128
#define H1_ 256
#define H2_ 128
#define LOG2E 1.4426950408889634f

typedef __attribute__((ext_vector_type(8))) short  s16x8;
typedef __attribute__((ext_vector_type(4))) float  f32x4;

// ws layout (bytes)
#define WS_WSUM  0          // f32 (W1a+W1c) frag-order K=128: 131072 B
#define WS_W1D   131072     // f32 W1d frag-order: 131072 B
#define WS_W2F   262144     // bf16 W2 frags: 65536 B
#define WS_Q2    327680     // f32 (W1b - W1c): 131072 B
#define WS_QB    458752     // f32 qb: 2048x256 -> 2097152 B

__device__ __forceinline__ unsigned short f2bf(float f) {
  union { float f; unsigned u; } v; v.f = f;
  unsigned r = v.u + 0x7fffu + ((v.u >> 16) & 1u);
  return (unsigned short)(r >> 16);
}
__device__ __forceinline__ unsigned pkbf(float lo, float hi) {
  __hip_bfloat162 h = __float22bfloat162_rn(float2{lo, hi});
  union { __hip_bfloat162 h; unsigned u; } v; v.h = h;
  return v.u;
}
// sigmoid(a + c) with nc = -LOG2E*c precomputed
__device__ __forceinline__ float sig_fused(float a, float nc) {
  float t = __builtin_amdgcn_exp2f(__builtin_fmaf(a, -LOG2E, nc));
  return __builtin_amdgcn_rcpf(1.0f + t);
}

// ---------------- prep: weight fragments (K=128 layer-1) + W2 frags + Q2 ----------------
__global__ __launch_bounds__(256)
void prep_weights(const float* __restrict__ W1, const float* __restrict__ W2,
                  float* __restrict__ wsum, float* __restrict__ w1d,
                  unsigned short* __restrict__ w2f, float* __restrict__ Q2)
{
  int g = blockIdx.x * 256 + threadIdx.x;
  if (g < 4096) {
    // layer-1 frags: c in [0,16), s in [0,4), l in [0,64)
    int c = g >> 8, s = (g >> 6) & 3, l = g & 63;
    int col = 16 * c + (l & 15);
#pragma unroll
    for (int j = 0; j < 8; ++j) {
      int k = 32 * s + 8 * (l >> 4) + j;
      wsum[(size_t)g * 8 + j] = W1[k * H1_ + col] + W1[(256 + k) * H1_ + col];
      w1d[(size_t)g * 8 + j]  = W1[(384 + k) * H1_ + col];
    }
  } else if (g < 8192) {
    int g2 = g - 4096;                       // c in [0,8), s in [0,8), l
    int c = g2 >> 9, s = (g2 >> 6) & 7, l = g2 & 63;
    int col = 16 * c + (l & 15);
#pragma unroll
    for (int j = 0; j < 8; ++j) {
      int k = 32 * s + 8 * (l >> 4) + j;
      w2f[(size_t)g2 * 8 + j] = f2bf(W2[k * H2_ + col]);
    }
  } else {
    int g3 = g - 8192;                       // 8192 float4 tasks over 128x256
    int e = g3 * 4;
    int d = e >> 8, h = e & 255;
#pragma unroll
    for (int j = 0; j < 4; ++j)
      Q2[e + j] = W1[(128 + d) * H1_ + h + j] - W1[(256 + d) * H1_ + h + j];
  }
}

// ---------------- prep: qb[b][h] = b1[h] + q[b] @ Q2 ----------------
__global__ __launch_bounds__(256)
void qb_prep(const float* __restrict__ query, const float* __restrict__ b1,
             const float* __restrict__ Q2, float* __restrict__ qb)
{
  __shared__ float q8[8 * 128];
  int b0 = blockIdx.x * 8;
  int tid = threadIdx.x;
  {
    const float4 v = *(const float4*)(query + (size_t)b0 * 128 + tid * 4);
    *(float4*)(q8 + tid * 4) = v;
  }
  __syncthreads();
  int h = tid;
  float acc[8];
#pragma unroll
  for (int j = 0; j < 8; ++j) acc[j] = b1[h];
  for (int d = 0; d < 128; ++d) {
    float w = Q2[d * 256 + h];
#pragma unroll
    for (int j = 0; j < 8; ++j) acc[j] += q8[j * 128 + d] * w;
  }
#pragma unroll
  for (int j = 0; j < 8; ++j) qb[(size_t)(b0 + j) * 256 + h] = acc[j];
}

#define MFMA16 __builtin_amdgcn_mfma_f32_16x16x32_bf16

// ---------------- main ----------------
__global__ __launch_bounds__(512, 4)
void attn_main(const float* __restrict__ query, const float* __restrict__ keys,
               const int* __restrict__ mask,
               const float* __restrict__ wsum, const float* __restrict__ w1d,
               const unsigned short* __restrict__ w2f,
               const float* __restrict__ qb_ws,
               const float* __restrict__ b2, const float* __restrict__ W3,
               const float* __restrict__ b3, float* __restrict__ out)
{
  __shared__ __align__(16) unsigned short Xc[2][64 * 128]; // 2x16KB keys bf16, swizzled
  __shared__ __align__(16) unsigned short H1c[64 * 256];   // 32KB swizzled
  __shared__ float qL[128];
  __shared__ float maskLf[256];
  __shared__ __align__(16) float scorep[64 * 8];

  // final-reduce buffers aliased into H1c (used only after the chunk loop)
  float* numredp = (float*)H1c;              // 8*128 floats
  float* denredp = numredp + 8 * 128;        // 8 floats

  const int b = blockIdx.x;
  const int tid = threadIdx.x;
  const int lane = tid & 63;
  const int wid = tid >> 6;

  if (tid < 128) qL[tid] = query[(size_t)b * 128 + tid];
  if (tid < 256)
    maskLf[tid] = (tid < T_) ? ((mask[(size_t)b * T_ + tid] == 1) ? 1.0f : 0.0f) : 0.0f;

  const float b3n = -LOG2E * b3[0];
  const float qn0 = -LOG2E * qb_ws[(size_t)b * 256 + wid * 16 + (lane & 15)];
  const float qn1 = -LOG2E * qb_ws[(size_t)b * 256 + (wid + 8) * 16 + (lane & 15)];

  // byte offset of this wave's W2 frag block (cb = wid): ((cb*8+s)*64+lane)*16B
  const unsigned w2off0 = (unsigned)(wid * 8192 + lane * 16);
  // byte offset of this lane's k2 quad (for b2/W3): k2 = wid*16 + (lane>>4)*4
  const unsigned k2off = (unsigned)((wid * 16 + ((lane >> 4) << 2)) * 4);

  // staging geometry (2 16B-units per thread)
  const int sp0 = tid * 2, sp1 = tid * 2 + 1;
  const int srow0 = sp0 >> 4, sc0s = sp0 & 15;
  const int srow1 = sp1 >> 4, sc1s = sp1 & 15;
  float4 pk[4];

// checked variant (only chunk 3 can exceed T)
#define LOADK(CH)                                                          \
  {                                                                        \
    int t0_ = (CH) * 64 + srow0, t1_ = (CH) * 64 + srow1;                  \
    if (t0_ < T_) {                                                        \
      const float* kp = keys + ((size_t)b * T_ + t0_) * 128 + 8 * sc0s;    \
      pk[0] = *(const float4*)kp; pk[1] = *(const float4*)(kp + 4);        \
    } else { pk[0] = make_float4(0,0,0,0); pk[1] = make_float4(0,0,0,0); } \
    if (t1_ < T_) {                                                        \
      const float* kp = keys + ((size_t)b * T_ + t1_) * 128 + 8 * sc1s;    \
      pk[2] = *(const float4*)kp; pk[3] = *(const float4*)(kp + 4);        \
    } else { pk[2] = make_float4(0,0,0,0); pk[3] = make_float4(0,0,0,0); } \
  }

// unchecked variant for chunks 0-2 (max t = 128+63 = 191 < 200)
#define LOADK_NC(CH)                                                       \
  {                                                                        \
    const float* kp0 = keys + ((size_t)b * T_ + (CH) * 64 + srow0) * 128 + 8 * sc0s; \
    pk[0] = *(const float4*)kp0; pk[1] = *(const float4*)(kp0 + 4);        \
    const float* kp1 = keys + ((size_t)b * T_ + (CH) * 64 + srow1) * 128 + 8 * sc1s; \
    pk[2] = *(const float4*)kp1; pk[3] = *(const float4*)(kp1 + 4);        \
  }

#define STAGE(CH)                                                          \
  {                                                                        \
    unsigned short* Xn = Xc[(CH) & 1];                                     \
    uint4 x0, x1;                                                          \
    unsigned* p0 = (unsigned*)&x0; unsigned* p1 = (unsigned*)&x1;          \
    p0[0] = pkbf(pk[0].x, pk[0].y); p0[1] = pkbf(pk[0].z, pk[0].w);        \
    p0[2] = pkbf(pk[1].x, pk[1].y); p0[3] = pkbf(pk[1].z, pk[1].w);        \
    p1[0] = pkbf(pk[2].x, pk[2].y); p1[1] = pkbf(pk[2].z, pk[2].w);        \
    p1[2] = pkbf(pk[3].x, pk[3].y); p1[3] = pkbf(pk[3].z, pk[3].w);        \
    *(uint4*)&Xn[(srow0 * 128 + 8 * sc0s) ^ ((srow0 & 15) << 3)] = x0;     \
    *(uint4*)&Xn[(srow1 * 128 + 8 * sc1s) ^ ((srow1 & 15) << 3)] = x1;     \
  }

  LOADK_NC(0);         // chunk-0 HBM loads in flight during preamble
  __syncthreads();     // qL / maskLf ready

  // ---- build persistent Wq frags: Wq = (W1a+W1c) + diag(q)*W1d, cols {wid, wid+8} ----
  s16x8 WqA[4], WqB[4];
#pragma unroll
  for (int s = 0; s < 4; ++s) {
    const int kb = 32 * s + 8 * (lane >> 4);
    const float4 q0 = *(const float4*)&qL[kb];
    const float4 q1 = *(const float4*)&qL[kb + 4];
    const float qk[8] = {q0.x, q0.y, q0.z, q0.w, q1.x, q1.y, q1.z, q1.w};
    {
      const float* wsp = wsum + ((size_t)(wid * 4 + s) * 64 + lane) * 8;
      const float* wdp = w1d  + ((size_t)(wid * 4 + s) * 64 + lane) * 8;
      s16x8 r;
#pragma unroll
      for (int j = 0; j < 8; ++j) r[j] = (short)f2bf(wsp[j] + qk[j] * wdp[j]);
      WqA[s] = r;
    }
    {
      const float* wsp = wsum + ((size_t)((wid + 8) * 4 + s) * 64 + lane) * 8;
      const float* wdp = w1d  + ((size_t)((wid + 8) * 4 + s) * 64 + lane) * 8;
      s16x8 r;
#pragma unroll
      for (int j = 0; j < 8; ++j) r[j] = (short)f2bf(wsp[j] + qk[j] * wdp[j]);
      WqB[s] = r;
    }
  }

  // ---- prologue: stage chunk 0, start chunk-1 loads ----
  STAGE(0);
  LOADK_NC(1);
  __syncthreads();

  float na0 = 0.f, na1 = 0.f, da = 0.f;

  for (int ch = 0; ch < 4; ++ch) {
    const int rem = T_ - ch * 64;                  // 64,64,64,8
    const int nrt = (rem >= 64) ? 4 : 1;
    const unsigned short* Xcur = Xc[ch & 1];

    // ---- P2: layer 1, wave owns cols {wid, wid+8}, K=128 ----
    {
      const int asw = (lane & 15) << 3;
      for (int rt = 0; rt < nrt; ++rt) {
        const int abase = (rt * 16 + (lane & 15)) * 128 + (lane >> 4) * 8;
        f32x4 a0 = {0,0,0,0}, a1 = {0,0,0,0};
        __builtin_amdgcn_s_setprio(1);
#pragma unroll
        for (int s = 0; s < 4; ++s) {
          const s16x8 Af = *(const s16x8*)&Xcur[(abase + s * 32) ^ asw];
          a0 = MFMA16(Af, WqA[s], a0, 0, 0, 0);
          a1 = MFMA16(Af, WqB[s], a1, 0, 0, 0);
        }
        __builtin_amdgcn_s_setprio(0);
#pragma unroll
        for (int i = 0; i < 4; ++i) {
          const int row = rt * 16 + (lane >> 4) * 4 + i;
          const int sw = (row & 15) << 3;
          const unsigned u = pkbf(sig_fused(a0[i], qn0), sig_fused(a1[i], qn1));
          H1c[(row * 256 + wid * 16 + (lane & 15)) ^ sw]       = (unsigned short)u;
          H1c[(row * 256 + (wid + 8) * 16 + (lane & 15)) ^ sw] = (unsigned short)(u >> 16);
        }
      }
    }

    // ---- stage NEXT chunk now: frees pk before P3 (register-pressure valley) ----
    if (ch < 3) STAGE(ch + 1);

    // ---- stream this chunk's W2 frags (L2); opaque offset prevents hoisting ----
    s16x8 Bf[8];
    {
      unsigned off = w2off0;
      asm volatile("" : "+v"(off));
#pragma unroll
      for (int s = 0; s < 8; ++s)
        Bf[s] = *(const s16x8*)((const char*)w2f + (size_t)off + (size_t)s * 1024);
    }
    __syncthreads();

    // ---- P3 (transposed): D[k2][t] = mfma(A=W2frag, B=H1frag) ----
    // lane holds t = tt*16 + (lane&15), k2 = wid*16 + (lane>>4)*4 + i
    // reduce over k2: 3 in-reg adds + shfl_xor(16) + shfl_xor(32)
    {
      const int asw = (lane & 15) << 3;
      unsigned off2 = k2off;
      asm volatile("" : "+v"(off2));
      const float4 bt  = *(const float4*)((const char*)b2 + off2);
      const float4 w3t = *(const float4*)((const char*)W3 + off2);
      const float4 nb2 = make_float4(-LOG2E * bt.x, -LOG2E * bt.y,
                                     -LOG2E * bt.z, -LOG2E * bt.w);
      for (int tt = 0; tt < nrt; ++tt) {
        const int ab = (tt * 16 + (lane & 15)) * 256 + (lane >> 4) * 8;
        f32x4 acc = {0,0,0,0};
        __builtin_amdgcn_s_setprio(1);
#pragma unroll
        for (int s = 0; s < 8; ++s) {
          const s16x8 Hf = *(const s16x8*)&H1c[(ab + s * 32) ^ asw];
          acc = MFMA16(Bf[s], Hf, acc, 0, 0, 0);
        }
        __builtin_amdgcn_s_setprio(0);
        float part = sig_fused(acc[0], nb2.x) * w3t.x
                   + sig_fused(acc[1], nb2.y) * w3t.y
                   + sig_fused(acc[2], nb2.z) * w3t.z
                   + sig_fused(acc[3], nb2.w) * w3t.w;
        part += __shfl_xor(part, 16);
        part += __shfl_xor(part, 32);
        if (lane < 16)
          scorep[(tt * 16 + lane) * 8 + wid] = part;
      }
    }
    __syncthreads();

    // ---- P4: finalize e, accumulate num/den; issue LOADK(ch+2) ----
    {
      if (ch == 0) { LOADK_NC(2); }
      else if (ch == 1) { LOADK(3); }
      float e = 0.0f;
      if (lane < 8) {
        const int row = wid * 8 + lane;
        const float4 s4a = *(const float4*)&scorep[row * 8];
        const float4 s4b = *(const float4*)&scorep[row * 8 + 4];
        const float ssum = (s4a.x + s4a.y) + (s4a.z + s4a.w)
                         + (s4b.x + s4b.y) + (s4b.z + s4b.w);
        const float sc = sig_fused(ssum, b3n);
        e = maskLf[ch * 64 + row] * __builtin_amdgcn_exp2f(sc * LOG2E);
      }
      const unsigned* Xc32 = (const unsigned*)Xcur;
#pragma unroll
      for (int r8 = 0; r8 < 8; ++r8) {
        const int row = wid * 8 + r8;
        const float ev = __shfl(e, r8);
        if (ev != 0.0f) {
          da += ev;
          const unsigned u = Xc32[(row * 64 + lane) ^ ((row & 15) << 2)];
          union { unsigned uu; float f; } lo, hi;
          lo.uu = u << 16; hi.uu = u & 0xffff0000u;
          na0 += ev * lo.f; na1 += ev * hi.f;
        }
      }
    }
    __syncthreads();
  }

  // ---- final reduce across the 8 waves (buffers aliased into H1c) ----
  *(float2*)&numredp[wid * 128 + 2 * lane] = make_float2(na0, na1);
  if (lane == 0) denredp[wid] = da;
  __syncthreads();
  if (tid < 128) {
    float num = 0.0f, den = 0.0f;
#pragma unroll
    for (int w = 0; w < 8; ++w) { num += numredp[w * 128 + tid]; den += denredp[w]; }
    out[(size_t)b * 128 + tid] = num / den;
  }
}

extern "C" void kernel_launch(void* const* d_in, const int* in_sizes, int n_in,
                              void* d_out, int out_size, void* d_ws, size_t ws_size,
                              hipStream_t stream) {
  const float* query = (const float*)d_in[0];
  const float* keys  = (const float*)d_in[1];
  const int*   mask  = (const int*)  d_in[2];
  const float* W1    = (const float*)d_in[3];
  const float* b1    = (const float*)d_in[4];
  const float* W2    = (const float*)d_in[5];
  const float* b2    = (const float*)d_in[6];
  const float* W3    = (const float*)d_in[7];
  const float* b3    = (const float*)d_in[8];
  float* out = (float*)d_out;

  char* ws = (char*)d_ws;
  float*          wsum = (float*)(ws + WS_WSUM);
  float*          w1dv = (float*)(ws + WS_W1D);
  unsigned short* w2f  = (unsigned short*)(ws + WS_W2F);
  float*          Q2   = (float*)(ws + WS_Q2);
  float*          qb   = (float*)(ws + WS_QB);

  prep_weights<<<64, 256, 0, stream>>>(W1, W2, wsum, w1dv, w2f, Q2);
  qb_prep<<<256, 256, 0, stream>>>(query, b1, Q2, qb);
  attn_main<<<B_, 512, 0, stream>>>(query, keys, mask, wsum, w1dv, w2f, qb,
                                    b2, W3, b3, out);
}

// Round 18
// 142.770 us; speedup vs baseline: 2.7458x; 2.7458x over previous
//
#include <hip/hip_runtime.h>
#include <hip/hip_bf16.h>

#define B_  2048
#define T_  200
#define D_  128
#define H1_ 256
#define H2_ 128
#define LOG2E 1.4426950408889634f

typedef __attribute__((ext_vector_type(8))) short  s16x8;
typedef __attribute__((ext_vector_type(4))) float  f32x4;

// ws layout (bytes)
#define WS_WSUM  0          // f32 (W1a+W1c) frag-order K=128: 131072 B
#define WS_W1D   131072     // f32 W1d frag-order: 131072 B
#define WS_W2F   262144     // bf16 W2 frags: 65536 B
#define WS_Q2    327680     // f32 (W1b - W1c): 131072 B
#define WS_QB    458752     // f32 qb: 2048x256 -> 2097152 B

__device__ __forceinline__ unsigned short f2bf(float f) {
  union { float f; unsigned u; } v; v.f = f;
  unsigned r = v.u + 0x7fffu + ((v.u >> 16) & 1u);
  return (unsigned short)(r >> 16);
}
__device__ __forceinline__ unsigned pkbf(float lo, float hi) {
  __hip_bfloat162 h = __float22bfloat162_rn(float2{lo, hi});
  union { __hip_bfloat162 h; unsigned u; } v; v.h = h;
  return v.u;
}
// sigmoid(a + c) with nc = -LOG2E*c precomputed
__device__ __forceinline__ float sig_fused(float a, float nc) {
  float t = __builtin_amdgcn_exp2f(__builtin_fmaf(a, -LOG2E, nc));
  return __builtin_amdgcn_rcpf(1.0f + t);
}

// ---------------- prep: weight fragments (K=128 layer-1) + W2 frags + Q2 ----------------
__global__ __launch_bounds__(256)
void prep_weights(const float* __restrict__ W1, const float* __restrict__ W2,
                  float* __restrict__ wsum, float* __restrict__ w1d,
                  unsigned short* __restrict__ w2f, float* __restrict__ Q2)
{
  int g = blockIdx.x * 256 + threadIdx.x;
  if (g < 4096) {
    // layer-1 frags: c in [0,16), s in [0,4), l in [0,64)
    int c = g >> 8, s = (g >> 6) & 3, l = g & 63;
    int col = 16 * c + (l & 15);
#pragma unroll
    for (int j = 0; j < 8; ++j) {
      int k = 32 * s + 8 * (l >> 4) + j;
      wsum[(size_t)g * 8 + j] = W1[k * H1_ + col] + W1[(256 + k) * H1_ + col];
      w1d[(size_t)g * 8 + j]  = W1[(384 + k) * H1_ + col];
    }
  } else if (g < 8192) {
    int g2 = g - 4096;                       // c in [0,8), s in [0,8), l
    int c = g2 >> 9, s = (g2 >> 6) & 7, l = g2 & 63;
    int col = 16 * c + (l & 15);
#pragma unroll
    for (int j = 0; j < 8; ++j) {
      int k = 32 * s + 8 * (l >> 4) + j;
      w2f[(size_t)g2 * 8 + j] = f2bf(W2[k * H2_ + col]);
    }
  } else {
    int g3 = g - 8192;                       // 8192 float4 tasks over 128x256
    int e = g3 * 4;
    int d = e >> 8, h = e & 255;
#pragma unroll
    for (int j = 0; j < 4; ++j)
      Q2[e + j] = W1[(128 + d) * H1_ + h + j] - W1[(256 + d) * H1_ + h + j];
  }
}

// ---------------- prep: qb[b][h] = b1[h] + q[b] @ Q2 ----------------
__global__ __launch_bounds__(256)
void qb_prep(const float* __restrict__ query, const float* __restrict__ b1,
             const float* __restrict__ Q2, float* __restrict__ qb)
{
  __shared__ float q8[8 * 128];
  int b0 = blockIdx.x * 8;
  int tid = threadIdx.x;
  {
    const float4 v = *(const float4*)(query + (size_t)b0 * 128 + tid * 4);
    *(float4*)(q8 + tid * 4) = v;
  }
  __syncthreads();
  int h = tid;
  float acc[8];
#pragma unroll
  for (int j = 0; j < 8; ++j) acc[j] = b1[h];
  for (int d = 0; d < 128; ++d) {
    float w = Q2[d * 256 + h];
#pragma unroll
    for (int j = 0; j < 8; ++j) acc[j] += q8[j * 128 + d] * w;
  }
#pragma unroll
  for (int j = 0; j < 8; ++j) qb[(size_t)(b0 + j) * 256 + h] = acc[j];
}

#define MFMA16 __builtin_amdgcn_mfma_f32_16x16x32_bf16

// ---------------- main ----------------
__global__ __launch_bounds__(512, 4)
void attn_main(const float* __restrict__ query, const float* __restrict__ keys,
               const int* __restrict__ mask,
               const float* __restrict__ wsum, const float* __restrict__ w1d,
               const unsigned short* __restrict__ w2f,
               const float* __restrict__ qb_ws,
               const float* __restrict__ b2, const float* __restrict__ W3,
               const float* __restrict__ b3, float* __restrict__ out)
{
  __shared__ __align__(16) unsigned short Xc[2][64 * 128]; // 2x16KB keys bf16, swizzled
  __shared__ __align__(16) unsigned short H1c[64 * 256];   // 32KB swizzled
  __shared__ float qL[128];
  __shared__ float maskLf[256];
  __shared__ __align__(16) float scorep[64 * 8];

  // final-reduce buffers aliased into H1c (used only after the chunk loop)
  float* numredp = (float*)H1c;              // 8*128 floats
  float* denredp = numredp + 8 * 128;        // 8 floats

  const int b = blockIdx.x;
  const int tid = threadIdx.x;
  const int lane = tid & 63;
  const int wid = tid >> 6;

  if (tid < 128) qL[tid] = query[(size_t)b * 128 + tid];
  if (tid < 256)
    maskLf[tid] = (tid < T_) ? ((mask[(size_t)b * T_ + tid] == 1) ? 1.0f : 0.0f) : 0.0f;

  const float b3n = -LOG2E * b3[0];
  const float qn0 = -LOG2E * qb_ws[(size_t)b * 256 + wid * 16 + (lane & 15)];
  const float qn1 = -LOG2E * qb_ws[(size_t)b * 256 + (wid + 8) * 16 + (lane & 15)];

  // byte offset of this wave's W2 frag block (cb = wid): ((cb*8+s)*64+lane)*16B
  const unsigned w2off0 = (unsigned)(wid * 8192 + lane * 16);
  // byte offset of this lane's k2 quad (for b2/W3): k2 = wid*16 + (lane>>4)*4
  const unsigned k2off = (unsigned)((wid * 16 + ((lane >> 4) << 2)) * 4);

  // staging geometry (2 16B-units per thread)
  const int sp0 = tid * 2, sp1 = tid * 2 + 1;
  const int srow0 = sp0 >> 4, sc0s = sp0 & 15;
  const int srow1 = sp1 >> 4, sc1s = sp1 & 15;
  float4 pk[4];

// checked variant (only chunk 3 can exceed T)
#define LOADK(CH)                                                          \
  {                                                                        \
    int t0_ = (CH) * 64 + srow0, t1_ = (CH) * 64 + srow1;                  \
    if (t0_ < T_) {                                                        \
      const float* kp = keys + ((size_t)b * T_ + t0_) * 128 + 8 * sc0s;    \
      pk[0] = *(const float4*)kp; pk[1] = *(const float4*)(kp + 4);        \
    } else { pk[0] = make_float4(0,0,0,0); pk[1] = make_float4(0,0,0,0); } \
    if (t1_ < T_) {                                                        \
      const float* kp = keys + ((size_t)b * T_ + t1_) * 128 + 8 * sc1s;    \
      pk[2] = *(const float4*)kp; pk[3] = *(const float4*)(kp + 4);        \
    } else { pk[2] = make_float4(0,0,0,0); pk[3] = make_float4(0,0,0,0); } \
  }

// unchecked variant for chunks 0-2 (max t = 128+63 = 191 < 200)
#define LOADK_NC(CH)                                                       \
  {                                                                        \
    const float* kp0 = keys + ((size_t)b * T_ + (CH) * 64 + srow0) * 128 + 8 * sc0s; \
    pk[0] = *(const float4*)kp0; pk[1] = *(const float4*)(kp0 + 4);        \
    const float* kp1 = keys + ((size_t)b * T_ + (CH) * 64 + srow1) * 128 + 8 * sc1s; \
    pk[2] = *(const float4*)kp1; pk[3] = *(const float4*)(kp1 + 4);        \
  }

#define STAGE(CH)                                                          \
  {                                                                        \
    unsigned short* Xn = Xc[(CH) & 1];                                     \
    uint4 x0, x1;                                                          \
    unsigned* p0 = (unsigned*)&x0; unsigned* p1 = (unsigned*)&x1;          \
    p0[0] = pkbf(pk[0].x, pk[0].y); p0[1] = pkbf(pk[0].z, pk[0].w);        \
    p0[2] = pkbf(pk[1].x, pk[1].y); p0[3] = pkbf(pk[1].z, pk[1].w);        \
    p1[0] = pkbf(pk[2].x, pk[2].y); p1[1] = pkbf(pk[2].z, pk[2].w);        \
    p1[2] = pkbf(pk[3].x, pk[3].y); p1[3] = pkbf(pk[3].z, pk[3].w);        \
    *(uint4*)&Xn[(srow0 * 128 + 8 * sc0s) ^ ((srow0 & 15) << 3)] = x0;     \
    *(uint4*)&Xn[(srow1 * 128 + 8 * sc1s) ^ ((srow1 & 15) << 3)] = x1;     \
  }

  LOADK_NC(0);         // chunk-0 HBM loads in flight during preamble
  __syncthreads();     // qL / maskLf ready

  // ---- build persistent Wq frags: Wq = (W1a+W1c) + diag(q)*W1d, cols {wid, wid+8} ----
  s16x8 WqA[4], WqB[4];
#pragma unroll
  for (int s = 0; s < 4; ++s) {
    const int kb = 32 * s + 8 * (lane >> 4);
    const float4 q0 = *(const float4*)&qL[kb];
    const float4 q1 = *(const float4*)&qL[kb + 4];
    const float qk[8] = {q0.x, q0.y, q0.z, q0.w, q1.x, q1.y, q1.z, q1.w};
    {
      const float* wsp = wsum + ((size_t)(wid * 4 + s) * 64 + lane) * 8;
      const float* wdp = w1d  + ((size_t)(wid * 4 + s) * 64 + lane) * 8;
      s16x8 r;
#pragma unroll
      for (int j = 0; j < 8; ++j) r[j] = (short)f2bf(wsp[j] + qk[j] * wdp[j]);
      WqA[s] = r;
    }
    {
      const float* wsp = wsum + ((size_t)((wid + 8) * 4 + s) * 64 + lane) * 8;
      const float* wdp = w1d  + ((size_t)((wid + 8) * 4 + s) * 64 + lane) * 8;
      s16x8 r;
#pragma unroll
      for (int j = 0; j < 8; ++j) r[j] = (short)f2bf(wsp[j] + qk[j] * wdp[j]);
      WqB[s] = r;
    }
  }

  // ---- prologue: stage chunk 0, start chunk-1 loads ----
  STAGE(0);
  LOADK_NC(1);
  __syncthreads();

  float na0 = 0.f, na1 = 0.f, da = 0.f;

  for (int ch = 0; ch < 4; ++ch) {
    const int rem = T_ - ch * 64;                  // 64,64,64,8
    const int nrt = (rem >= 64) ? 4 : 1;
    const unsigned short* Xcur = Xc[ch & 1];

    // ---- P2: layer 1, wave owns cols {wid, wid+8}, K=128 ----
    {
      const int asw = (lane & 15) << 3;
      for (int rt = 0; rt < nrt; ++rt) {
        const int abase = (rt * 16 + (lane & 15)) * 128 + (lane >> 4) * 8;
        f32x4 a0 = {0,0,0,0}, a1 = {0,0,0,0};
#pragma unroll
        for (int s = 0; s < 4; ++s) {
          const s16x8 Af = *(const s16x8*)&Xcur[(abase + s * 32) ^ asw];
          a0 = MFMA16(Af, WqA[s], a0, 0, 0, 0);
          a1 = MFMA16(Af, WqB[s], a1, 0, 0, 0);
        }
#pragma unroll
        for (int i = 0; i < 4; ++i) {
          const int row = rt * 16 + (lane >> 4) * 4 + i;
          const int sw = (row & 15) << 3;
          H1c[(row * 256 + wid * 16 + (lane & 15)) ^ sw]       = f2bf(sig_fused(a0[i], qn0));
          H1c[(row * 256 + (wid + 8) * 16 + (lane & 15)) ^ sw] = f2bf(sig_fused(a1[i], qn1));
        }
      }
    }

    // ---- stage NEXT chunk now: frees pk before P3 (register-pressure valley) ----
    if (ch < 3) STAGE(ch + 1);

    // ---- stream this chunk's W2 frags (L2); opaque offset prevents hoisting ----
    s16x8 Bf[8];
    {
      unsigned off = w2off0;
      asm volatile("" : "+v"(off));
#pragma unroll
      for (int s = 0; s < 8; ++s)
        Bf[s] = *(const s16x8*)((const char*)w2f + (size_t)off + (size_t)s * 1024);
    }
    __syncthreads();

    // ---- P3 (transposed): D[k2][t] = mfma(A=W2frag, B=H1frag) ----
    // lane holds t = tt*16 + (lane&15), k2 = wid*16 + (lane>>4)*4 + i
    // reduce over k2: 3 in-reg adds + shfl_xor(16) + shfl_xor(32)
    {
      const int asw = (lane & 15) << 3;
      unsigned off2 = k2off;
      asm volatile("" : "+v"(off2));
      const float4 bt  = *(const float4*)((const char*)b2 + off2);
      const float4 w3t = *(const float4*)((const char*)W3 + off2);
      for (int tt = 0; tt < nrt; ++tt) {
        const int ab = (tt * 16 + (lane & 15)) * 256 + (lane >> 4) * 8;
        f32x4 acc = {0,0,0,0};
#pragma unroll
        for (int s = 0; s < 8; ++s) {
          const s16x8 Hf = *(const s16x8*)&H1c[(ab + s * 32) ^ asw];
          acc = MFMA16(Bf[s], Hf, acc, 0, 0, 0);
        }
        float part = sig_fused(acc[0], -LOG2E * bt.x) * w3t.x
                   + sig_fused(acc[1], -LOG2E * bt.y) * w3t.y
                   + sig_fused(acc[2], -LOG2E * bt.z) * w3t.z
                   + sig_fused(acc[3], -LOG2E * bt.w) * w3t.w;
        part += __shfl_xor(part, 16);
        part += __shfl_xor(part, 32);
        if (lane < 16)
          scorep[(tt * 16 + lane) * 8 + wid] = part;
      }
    }
    __syncthreads();

    // ---- P4: finalize e, accumulate num/den; issue LOADK(ch+2) ----
    {
      if (ch == 0) { LOADK_NC(2); }
      else if (ch == 1) { LOADK(3); }
      float e = 0.0f;
      if (lane < 8) {
        const int row = wid * 8 + lane;
        const float4 s4a = *(const float4*)&scorep[row * 8];
        const float4 s4b = *(const float4*)&scorep[row * 8 + 4];
        const float ssum = (s4a.x + s4a.y) + (s4a.z + s4a.w)
                         + (s4b.x + s4b.y) + (s4b.z + s4b.w);
        const float sc = sig_fused(ssum, b3n);
        e = maskLf[ch * 64 + row] * __builtin_amdgcn_exp2f(sc * LOG2E);
      }
      const unsigned* Xc32 = (const unsigned*)Xcur;
#pragma unroll
      for (int r8 = 0; r8 < 8; ++r8) {
        const int row = wid * 8 + r8;
        const float ev = __shfl(e, r8);
        if (ev != 0.0f) {
          da += ev;
          const unsigned u = Xc32[(row * 64 + lane) ^ ((row & 15) << 2)];
          union { unsigned uu; float f; } lo, hi;
          lo.uu = u << 16; hi.uu = u & 0xffff0000u;
          na0 += ev * lo.f; na1 += ev * hi.f;
        }
      }
    }
    __syncthreads();
  }

  // ---- final reduce across the 8 waves (buffers aliased into H1c) ----
  *(float2*)&numredp[wid * 128 + 2 * lane] = make_float2(na0, na1);
  if (lane == 0) denredp[wid] = da;
  __syncthreads();
  if (tid < 128) {
    float num = 0.0f, den = 0.0f;
#pragma unroll
    for (int w = 0; w < 8; ++w) { num += numredp[w * 128 + tid]; den += denredp[w]; }
    out[(size_t)b * 128 + tid] = num / den;
  }
}

extern "C" void kernel_launch(void* const* d_in, const int* in_sizes, int n_in,
                              void* d_out, int out_size, void* d_ws, size_t ws_size,
                              hipStream_t stream) {
  const float* query = (const float*)d_in[0];
  const float* keys  = (const float*)d_in[1];
  const int*   mask  = (const int*)  d_in[2];
  const float* W1    = (const float*)d_in[3];
  const float* b1    = (const float*)d_in[4];
  const float* W2    = (const float*)d_in[5];
  const float* b2    = (const float*)d_in[6];
  const float* W3    = (const float*)d_in[7];
  const float* b3    = (const float*)d_in[8];
  float* out = (float*)d_out;

  char* ws = (char*)d_ws;
  float*          wsum = (float*)(ws + WS_WSUM);
  float*          w1dv = (float*)(ws + WS_W1D);
  unsigned short* w2f  = (unsigned short*)(ws + WS_W2F);
  float*          Q2   = (float*)(ws + WS_Q2);
  float*          qb   = (float*)(ws + WS_QB);

  prep_weights<<<64, 256, 0, stream>>>(W1, W2, wsum, w1dv, w2f, Q2);
  qb_prep<<<256, 256, 0, stream>>>(query, b1, Q2, qb);
  attn_main<<<B_, 512, 0, stream>>>(query, keys, mask, wsum, w1dv, w2f, qb,
                                    b2, W3, b3, out);
}